// Round 7
// baseline (411.357 us; speedup 1.0000x reference)
//
#include <hip/hip_runtime.h>

#define U_CNT 100000
#define I_CNT 50000
#define D_DIM 64
#define N_NODES 150000            // U + I
#define CHUNK 2048                // edges per block in passes A/B
#define NBKT 586                  // ceil(N_NODES/256) coarse buckets (256 nodes each)
#define SCAN_BLK 512
#define CCAP 3584                 // LDS edge cache per bucket (max bucket ~3.4K)
#define FUSE_GRID 512             // co-residency guaranteed by __launch_bounds__(256,2)

// ---------- bf16 helpers ----------
__device__ __forceinline__ float blo(unsigned u) { return __uint_as_float(u << 16); }
__device__ __forceinline__ float bhi(unsigned u) { return __uint_as_float(u & 0xFFFF0000u); }
__device__ __forceinline__ unsigned f2b(float f) {  // fp32 -> bf16 bits, RNE
    unsigned b = __float_as_uint(f);
    return (b + 0x7FFFu + ((b >> 16) & 1u)) >> 16;
}
__device__ __forceinline__ unsigned pack2(float a, float b) {
    return f2b(a) | (f2b(b) << 16);
}

// ---------- Pass A: coarse LDS histogram (+ fused fp32->bf16 convert) ----------
__global__ void bucket_hist(const int* __restrict__ dst, int* __restrict__ H,
                            int NB_B, int nE,
                            const float4* __restrict__ user4,
                            const float4* __restrict__ item4,
                            uint2* __restrict__ ego0, int n4u, int n4) {
    __shared__ int h[NBKT];
    for (int i = threadIdx.x; i < NBKT; i += blockDim.x) h[i] = 0;
    __syncthreads();
    int b = blockIdx.x;
    int beg = b * CHUNK, end = min(nE, beg + CHUNK);
    for (int e = beg + (int)threadIdx.x; e < end; e += blockDim.x)
        atomicAdd(&h[dst[e] >> 8], 1);
    __syncthreads();
    for (int i = threadIdx.x; i < NBKT; i += blockDim.x) H[i * NB_B + b] = h[i];
    int gsz = gridDim.x * blockDim.x;
    for (int i = blockIdx.x * blockDim.x + threadIdx.x; i < n4; i += gsz) {
        float4 f = (i < n4u) ? user4[i] : item4[i - n4u];
        ego0[i] = make_uint2(pack2(f.x, f.y), pack2(f.z, f.w));
    }
}

// ---------- exclusive scan over H ----------
__global__ void block_sums(const int* __restrict__ in, int* __restrict__ blksum, int n) {
    __shared__ int sm[SCAN_BLK];
    int i = blockIdx.x * SCAN_BLK + threadIdx.x;
    sm[threadIdx.x] = (i < n) ? in[i] : 0;
    __syncthreads();
    for (int off = SCAN_BLK / 2; off > 0; off >>= 1) {
        if (threadIdx.x < off) sm[threadIdx.x] += sm[threadIdx.x + off];
        __syncthreads();
    }
    if (threadIdx.x == 0) blksum[blockIdx.x] = sm[0];
}

__global__ void scan_blksums(const int* __restrict__ blksum, int* __restrict__ blkoff, int nb) {
    __shared__ int sm[1024];
    int t = threadIdx.x;
    int v = (t < nb) ? blksum[t] : 0;
    sm[t] = v;
    __syncthreads();
    for (int off = 1; off < 1024; off <<= 1) {
        int x = (t >= off) ? sm[t - off] : 0;
        __syncthreads();
        sm[t] += x;
        __syncthreads();
    }
    if (t < nb) blkoff[t] = sm[t] - v;  // exclusive
}

__global__ void scan_within(int* __restrict__ H, const int* __restrict__ blkoff, int n) {
    __shared__ int sm[SCAN_BLK];
    int i = blockIdx.x * SCAN_BLK + threadIdx.x;
    int t = threadIdx.x;
    int d = (i < n) ? H[i] : 0;
    sm[t] = d;
    __syncthreads();
    for (int off = 1; off < SCAN_BLK; off <<= 1) {
        int x = (t >= off) ? sm[t - off] : 0;
        __syncthreads();
        sm[t] += x;
        __syncthreads();
    }
    if (i < n) H[i] = blkoff[blockIdx.x] + sm[t] - d;
}

// ---------- Pass B: scatter edges into coarse buckets ----------
__global__ void bucket_scatter(const int* __restrict__ src, const int* __restrict__ dst,
                               const float* __restrict__ val, const int* __restrict__ Hs,
                               uint2* __restrict__ tmp, int NB_B, int nE) {
    __shared__ int cur[NBKT];
    int b = blockIdx.x;
    for (int i = threadIdx.x; i < NBKT; i += blockDim.x) cur[i] = Hs[i * NB_B + b];
    __syncthreads();
    int beg = b * CHUNK, end = min(nE, beg + CHUNK);
    for (int e = beg + (int)threadIdx.x; e < end; e += blockDim.x) {
        int d = dst[e];
        int pos = atomicAdd(&cur[d >> 8], 1);
        tmp[pos] = make_uint2((unsigned)src[e] | ((unsigned)(d & 255) << 18),
                              __float_as_uint(val[e]));
    }
}

// ---------- Pass C: per-bucket fine sort -> csr + row_ptr ----------
__global__ void bucket_build(const int* __restrict__ Hs, const uint2* __restrict__ tmp,
                             int2* __restrict__ csr, int* __restrict__ row_ptr,
                             int NB_B, int nE) {
    __shared__ int hist[256];
    __shared__ int scanbuf[256];
    __shared__ int cur[256];
    __shared__ uint2 cache[CCAP];
    int bkt  = blockIdx.x;
    int base = Hs[(size_t)bkt * NB_B];
    int endp = (bkt + 1 < NBKT) ? Hs[(size_t)(bkt + 1) * NB_B] : nE;
    int size = endp - base;
    int nbins = min(256, N_NODES - bkt * 256);
    int t = threadIdx.x;

    hist[t] = 0;
    __syncthreads();
    bool cached = (size <= CCAP);
    for (int k = t; k < size; k += blockDim.x) {
        uint2 r = tmp[base + k];
        if (cached) cache[k] = r;
        atomicAdd(&hist[(r.x >> 18) & 255], 1);
    }
    __syncthreads();
    int v = hist[t];
    scanbuf[t] = v;
    __syncthreads();
    for (int off = 1; off < 256; off <<= 1) {
        int x = (t >= off) ? scanbuf[t - off] : 0;
        __syncthreads();
        scanbuf[t] += x;
        __syncthreads();
    }
    int ex = scanbuf[t] - v;
    if (t < nbins) row_ptr[bkt * 256 + t] = base + ex;
    cur[t] = ex;
    __syncthreads();
    if (bkt == NBKT - 1) {
        if (t == 0) row_ptr[N_NODES] = nE;
        if (t < 4)  csr[nE + t] = make_int2(0, 0);  // spmm prefetch pad
    }
    for (int k = t; k < size; k += blockDim.x) {
        uint2 r = cached ? cache[k] : tmp[base + k];
        int f = (r.x >> 18) & 255;
        int p = atomicAdd(&cur[f], 1);
        csr[base + p] = make_int2((int)(r.x & 0x3FFFFu), (int)r.y);
    }
}

// ---------- fused 3-layer SpMM (persistent, software grid barrier) ----------
__device__ __forceinline__ void fma8(float (&acc)[8], float v, uint4 g) {
    acc[0] = fmaf(v, blo(g.x), acc[0]); acc[1] = fmaf(v, bhi(g.x), acc[1]);
    acc[2] = fmaf(v, blo(g.y), acc[2]); acc[3] = fmaf(v, bhi(g.y), acc[3]);
    acc[4] = fmaf(v, blo(g.z), acc[4]); acc[5] = fmaf(v, bhi(g.z), acc[5]);
    acc[6] = fmaf(v, blo(g.w), acc[6]); acc[7] = fmaf(v, bhi(g.w), acc[7]);
}

// agent-scope release-add + acquire-spin; monotonic counter, no reset needed.
__device__ __forceinline__ void grid_bar(int* bar, int target) {
    __syncthreads();
    if (threadIdx.x == 0) {
        __hip_atomic_fetch_add(bar, 1, __ATOMIC_ACQ_REL, __HIP_MEMORY_SCOPE_AGENT);
        while (__hip_atomic_load(bar, __ATOMIC_ACQUIRE, __HIP_MEMORY_SCOPE_AGENT) < target)
            __builtin_amdgcn_s_sleep(4);
    }
    __syncthreads();
}

template <int FINAL>
__device__ __forceinline__ void spmm_rows(int g0, int ngroups, int l,
                                          const int* __restrict__ row_ptr,
                                          const int2* __restrict__ csr,
                                          const uint4* __restrict__ ego_in,
                                          uint4* __restrict__ ego_out,
                                          const uint4* __restrict__ egoA,
                                          const uint4* __restrict__ egoB,
                                          float4* __restrict__ out) {
    for (int node = g0; node < N_NODES; node += ngroups) {
        int beg = row_ptr[node];
        int end = row_ptr[node + 1];
        float a0[8] = {0, 0, 0, 0, 0, 0, 0, 0};
        float a1[8] = {0, 0, 0, 0, 0, 0, 0, 0};
        int2 e0 = csr[beg], e1 = csr[beg + 1], e2 = csr[beg + 2], e3 = csr[beg + 3];
        int j = beg;
        while (j + 4 <= end) {
            uint4 x0 = ego_in[(size_t)e0.x * 8 + l];
            uint4 x1 = ego_in[(size_t)e1.x * 8 + l];
            uint4 x2 = ego_in[(size_t)e2.x * 8 + l];
            uint4 x3 = ego_in[(size_t)e3.x * 8 + l];
            int2 n0 = csr[j + 4], n1 = csr[j + 5], n2 = csr[j + 6], n3 = csr[j + 7];
            fma8(a0, __int_as_float(e0.y), x0);
            fma8(a1, __int_as_float(e1.y), x1);
            fma8(a0, __int_as_float(e2.y), x2);
            fma8(a1, __int_as_float(e3.y), x3);
            e0 = n0; e1 = n1; e2 = n2; e3 = n3;
            j += 4;
        }
        int rem = end - j;  // 0..3
        if (rem > 0) fma8(a0, __int_as_float(e0.y), ego_in[(size_t)e0.x * 8 + l]);
        if (rem > 1) fma8(a1, __int_as_float(e1.y), ego_in[(size_t)e1.x * 8 + l]);
        if (rem > 2) fma8(a0, __int_as_float(e2.y), ego_in[(size_t)e2.x * 8 + l]);

        float acc[8];
#pragma unroll
        for (int k = 0; k < 8; ++k) acc[k] = a0[k] + a1[k];

        if (!FINAL) {
            uint4 r;
            r.x = pack2(acc[0], acc[1]); r.y = pack2(acc[2], acc[3]);
            r.z = pack2(acc[4], acc[5]); r.w = pack2(acc[6], acc[7]);
            ego_out[(size_t)node * 8 + l] = r;
        } else {
            uint4 a = egoA[(size_t)node * 8 + l];
            uint4 b = egoB[(size_t)node * 8 + l];
            const float s = 1.0f / 3.0f;
            float4 o0, o1;
            o0.x = (blo(a.x) + blo(b.x) + acc[0]) * s;
            o0.y = (bhi(a.x) + bhi(b.x) + acc[1]) * s;
            o0.z = (blo(a.y) + blo(b.y) + acc[2]) * s;
            o0.w = (bhi(a.y) + bhi(b.y) + acc[3]) * s;
            o1.x = (blo(a.z) + blo(b.z) + acc[4]) * s;
            o1.y = (bhi(a.z) + bhi(b.z) + acc[5]) * s;
            o1.z = (blo(a.w) + blo(b.w) + acc[6]) * s;
            o1.w = (bhi(a.w) + bhi(b.w) + acc[7]) * s;
            size_t ob = (size_t)node * 16 + 2 * l;
            out[ob]     = o0;
            out[ob + 1] = o1;
        }
    }
}

__global__ __launch_bounds__(256, 2)  // ≥2 blocks/CU capacity → 512 blocks co-resident
void lgcn_spmm_fused(const int* __restrict__ row_ptr,
                     const int2* __restrict__ csr,
                     const uint4* __restrict__ ego0,
                     uint4* __restrict__ ego_a,
                     uint4* __restrict__ ego_b,
                     float4* __restrict__ out,
                     int* __restrict__ bar) {
    const int ngroups = (gridDim.x * blockDim.x) >> 3;          // 16384
    const int g0 = (blockIdx.x * blockDim.x + threadIdx.x) >> 3;
    const int l  = threadIdx.x & 7;
    spmm_rows<0>(g0, ngroups, l, row_ptr, csr, ego0, ego_a, nullptr, nullptr, nullptr);
    grid_bar(bar, (int)gridDim.x);
    spmm_rows<0>(g0, ngroups, l, row_ptr, csr, ego_a, ego_b, nullptr, nullptr, nullptr);
    grid_bar(bar, 2 * (int)gridDim.x);
    spmm_rows<1>(g0, ngroups, l, row_ptr, csr, ego_b, nullptr, ego_a, ego_b, out);
}

static inline size_t align_up(size_t x, size_t a) { return (x + a - 1) & ~(a - 1); }

extern "C" void kernel_launch(void* const* d_in, const int* in_sizes, int n_in,
                              void* d_out, int out_size, void* d_ws, size_t ws_size,
                              hipStream_t stream) {
    const float* user_emb  = (const float*)d_in[0];
    const float* item_emb  = (const float*)d_in[1];
    const int*   edge_src  = (const int*)d_in[2];
    const int*   edge_dst  = (const int*)d_in[3];
    const float* edge_vals = (const float*)d_in[4];
    const int    nE        = in_sizes[2];  // 2E = 1.2M

    float* out = (float*)d_out;
    const size_t nd = (size_t)N_NODES * D_DIM;

    const int NB_B = (nE + CHUNK - 1) / CHUNK;           // 586
    const int nH   = NBKT * NB_B;                        // ~343K
    const int NBs  = (nH + SCAN_BLK - 1) / SCAN_BLK;     // 671 (<=1024)

    // ---- ws layout ----
    size_t off = 0;
    char* base = (char*)d_ws;
    int2*  csr     = (int2*)(base + off);  off = align_up(off + (size_t)(nE + 4) * sizeof(int2), 256);
    int*   row_ptr = (int*)(base + off);   off = align_up(off + (size_t)(N_NODES + 1) * 4, 256);
    uint2* tmp     = (uint2*)(base + off); off = align_up(off + (size_t)nE * sizeof(uint2), 256);
    int*   H       = (int*)(base + off);   off = align_up(off + (size_t)nH * 4, 256);
    int*   blksum  = (int*)(base + off);   off = align_up(off + (size_t)NBs * 4, 256);
    int*   blkoff  = (int*)(base + off);   off = align_up(off + (size_t)NBs * 4, 256);
    uint4* ego0    = (uint4*)(base + off); off = align_up(off + (size_t)N_NODES * 128, 256);
    uint4* ego_a   = (uint4*)(base + off); off = align_up(off + (size_t)N_NODES * 128, 256);
    uint4* ego_b   = (uint4*)(base + off); off = align_up(off + (size_t)N_NODES * 128, 256);
    int*   bar     = (int*)(base + off);   off = align_up(off + 256, 256);

    const int block = 256;
    const int n4  = (int)(nd / 4);
    const int n4u = U_CNT * D_DIM / 4;

    // barrier counter must start at 0 (ws is poisoned 0xAA)
    hipMemsetAsync(bar, 0, 64, stream);

    // ---- atomic-free CSR build ----
    bucket_hist<<<NB_B, block, 0, stream>>>(edge_dst, H, NB_B, nE,
        (const float4*)user_emb, (const float4*)item_emb, (uint2*)ego0, n4u, n4);
    block_sums<<<NBs, SCAN_BLK, 0, stream>>>(H, blksum, nH);
    scan_blksums<<<1, 1024, 0, stream>>>(blksum, blkoff, NBs);
    scan_within<<<NBs, SCAN_BLK, 0, stream>>>(H, blkoff, nH);
    bucket_scatter<<<NB_B, block, 0, stream>>>(edge_src, edge_dst, edge_vals, H, tmp, NB_B, nE);
    bucket_build<<<NBKT, block, 0, stream>>>(H, tmp, csr, row_ptr, NB_B, nE);

    // ---- fused 3-layer SpMM ----
    lgcn_spmm_fused<<<FUSE_GRID, block, 0, stream>>>(
        row_ptr, csr, ego0, ego_a, ego_b, (float4*)out, bar);
}

// Round 8
// 258.034 us; speedup vs baseline: 1.5942x; 1.5942x over previous
//
#include <hip/hip_runtime.h>

#define U_CNT 100000
#define I_CNT 50000
#define D_DIM 64
#define N_NODES 150000            // U + I
#define CHUNK 4096                // edges per block in passes A/B
#define NBKT 586                  // ceil(N_NODES/256) coarse buckets (256 nodes each)
#define SCAN_BLK 512
#define CCAP 3584                 // LDS edge cache per bucket (max bucket ~3.4K)

typedef float fx4 __attribute__((ext_vector_type(4)));

// ---------- bf16 helpers ----------
__device__ __forceinline__ float blo(unsigned u) { return __uint_as_float(u << 16); }
__device__ __forceinline__ float bhi(unsigned u) { return __uint_as_float(u & 0xFFFF0000u); }
__device__ __forceinline__ unsigned f2b(float f) {  // fp32 -> bf16 bits, RNE
    unsigned b = __float_as_uint(f);
    return (b + 0x7FFFu + ((b >> 16) & 1u)) >> 16;
}
__device__ __forceinline__ unsigned pack2(float a, float b) {
    return f2b(a) | (f2b(b) << 16);
}

// non-temporal int2 load (csr entries are streamed once — keep L2 for ego rows)
__device__ __forceinline__ int2 ldnt2(const int2* p) {
    unsigned long long r = __builtin_nontemporal_load((const unsigned long long*)p);
    int2 v;
    v.x = (int)(unsigned)(r & 0xFFFFFFFFull);
    v.y = (int)(unsigned)(r >> 32);
    return v;
}

// ---------- Pass A: coarse LDS histogram (+ fused fp32->bf16 convert) ----------
__global__ void bucket_hist(const int* __restrict__ dst, int* __restrict__ H,
                            int NB_B, int nE,
                            const fx4* __restrict__ user4,
                            const fx4* __restrict__ item4,
                            uint2* __restrict__ ego0, int n4u, int n4) {
    __shared__ int h[NBKT];
    for (int i = threadIdx.x; i < NBKT; i += blockDim.x) h[i] = 0;
    __syncthreads();
    int b = blockIdx.x;
    int beg = b * CHUNK, end = min(nE, beg + CHUNK);
    for (int e = beg + (int)threadIdx.x; e < end; e += blockDim.x)
        atomicAdd(&h[dst[e] >> 8], 1);
    __syncthreads();
    for (int i = threadIdx.x; i < NBKT; i += blockDim.x) H[i * NB_B + b] = h[i];
    // fused streaming convert (read-once inputs -> non-temporal)
    int gsz = gridDim.x * blockDim.x;
    for (int i = blockIdx.x * blockDim.x + threadIdx.x; i < n4; i += gsz) {
        fx4 f = (i < n4u) ? __builtin_nontemporal_load(&user4[i])
                          : __builtin_nontemporal_load(&item4[i - n4u]);
        ego0[i] = make_uint2(pack2(f.x, f.y), pack2(f.z, f.w));
    }
}

// ---------- scan over H (nH = NBKT * NB_B ~= 172K), 2 kernels ----------
__global__ void block_sums(const int* __restrict__ in, int* __restrict__ blksum, int n) {
    __shared__ int sm[SCAN_BLK];
    int i = blockIdx.x * SCAN_BLK + threadIdx.x;
    sm[threadIdx.x] = (i < n) ? in[i] : 0;
    __syncthreads();
    for (int off = SCAN_BLK / 2; off > 0; off >>= 1) {
        if (threadIdx.x < off) sm[threadIdx.x] += sm[threadIdx.x + off];
        __syncthreads();
    }
    if (threadIdx.x == 0) blksum[blockIdx.x] = sm[0];
}

// in-place exclusive scan; each block derives its own offset from blksum[0..b)
__global__ void scan_within(int* __restrict__ H, const int* __restrict__ blksum, int n) {
    __shared__ int sm[SCAN_BLK];
    __shared__ int red[SCAN_BLK];
    int b = blockIdx.x;
    int t = threadIdx.x;
    // block offset = sum of predecessor block sums
    int part = 0;
    for (int i = t; i < b; i += SCAN_BLK) part += blksum[i];
    red[t] = part;
    __syncthreads();
    for (int off = SCAN_BLK / 2; off > 0; off >>= 1) {
        if (t < off) red[t] += red[t + off];
        __syncthreads();
    }
    int blkoff = red[0];
    // within-block Hillis-Steele
    int i = b * SCAN_BLK + t;
    int d = (i < n) ? H[i] : 0;
    sm[t] = d;
    __syncthreads();
    for (int off = 1; off < SCAN_BLK; off <<= 1) {
        int x = (t >= off) ? sm[t - off] : 0;
        __syncthreads();
        sm[t] += x;
        __syncthreads();
    }
    if (i < n) H[i] = blkoff + sm[t] - d;
}

// ---------- Pass B: scatter edges into coarse buckets (LDS cursors) ----------
__global__ void bucket_scatter(const int* __restrict__ src, const int* __restrict__ dst,
                               const float* __restrict__ val, const int* __restrict__ Hs,
                               uint2* __restrict__ tmp, int NB_B, int nE) {
    __shared__ int cur[NBKT];
    int b = blockIdx.x;
    for (int i = threadIdx.x; i < NBKT; i += blockDim.x) cur[i] = Hs[i * NB_B + b];
    __syncthreads();
    int beg = b * CHUNK, end = min(nE, beg + CHUNK);
    for (int e = beg + (int)threadIdx.x; e < end; e += blockDim.x) {
        int d = dst[e];
        int pos = atomicAdd(&cur[d >> 8], 1);
        tmp[pos] = make_uint2((unsigned)src[e] | ((unsigned)(d & 255) << 18),
                              __float_as_uint(val[e]));
    }
}

// ---------- Pass C: per-bucket fine sort -> csr + row_ptr ----------
__global__ void bucket_build(const int* __restrict__ Hs, const uint2* __restrict__ tmp,
                             int2* __restrict__ csr, int* __restrict__ row_ptr,
                             int NB_B, int nE) {
    __shared__ int hist[256];
    __shared__ int scanbuf[256];
    __shared__ int cur[256];
    __shared__ uint2 cache[CCAP];
    int bkt  = blockIdx.x;
    int base = Hs[(size_t)bkt * NB_B];
    int endp = (bkt + 1 < NBKT) ? Hs[(size_t)(bkt + 1) * NB_B] : nE;
    int size = endp - base;
    int nbins = min(256, N_NODES - bkt * 256);
    int t = threadIdx.x;

    hist[t] = 0;
    __syncthreads();
    bool cached = (size <= CCAP);
    for (int k = t; k < size; k += blockDim.x) {
        uint2 r = tmp[base + k];
        if (cached) cache[k] = r;
        atomicAdd(&hist[(r.x >> 18) & 255], 1);
    }
    __syncthreads();
    int v = hist[t];
    scanbuf[t] = v;
    __syncthreads();
    for (int off = 1; off < 256; off <<= 1) {
        int x = (t >= off) ? scanbuf[t - off] : 0;
        __syncthreads();
        scanbuf[t] += x;
        __syncthreads();
    }
    int ex = scanbuf[t] - v;
    if (t < nbins) row_ptr[bkt * 256 + t] = base + ex;
    cur[t] = ex;
    __syncthreads();
    if (bkt == NBKT - 1) {
        if (t == 0) row_ptr[N_NODES] = nE;
        if (t < 4)  csr[nE + t] = make_int2(0, 0);  // spmm prefetch pad
    }
    for (int k = t; k < size; k += blockDim.x) {
        uint2 r = cached ? cache[k] : tmp[base + k];
        int f = (r.x >> 18) & 255;
        int p = atomicAdd(&cur[f], 1);
        csr[base + p] = make_int2((int)(r.x & 0x3FFFFu), (int)r.y);
    }
}

// ---------- gather SpMM: 8 lanes/node, 16 B (8 bf16) per lane ----------
__device__ __forceinline__ void fma8(float (&acc)[8], float v, uint4 g) {
    acc[0] = fmaf(v, blo(g.x), acc[0]); acc[1] = fmaf(v, bhi(g.x), acc[1]);
    acc[2] = fmaf(v, blo(g.y), acc[2]); acc[3] = fmaf(v, bhi(g.y), acc[3]);
    acc[4] = fmaf(v, blo(g.z), acc[4]); acc[5] = fmaf(v, bhi(g.z), acc[5]);
    acc[6] = fmaf(v, blo(g.w), acc[6]); acc[7] = fmaf(v, bhi(g.w), acc[7]);
}

template <int FINAL>
__global__ void lgcn_spmm(const int* __restrict__ row_ptr,
                          const int2* __restrict__ csr,
                          const uint4* __restrict__ ego_in,
                          uint4* __restrict__ ego_out,
                          const uint4* __restrict__ egoA,
                          const uint4* __restrict__ egoB,
                          float* __restrict__ out) {
    int node = (blockIdx.x * blockDim.x + threadIdx.x) >> 3;
    int l    = threadIdx.x & 7;
    if (node >= N_NODES) return;
    int beg = row_ptr[node];
    int end = row_ptr[node + 1];

    float a0[8] = {0, 0, 0, 0, 0, 0, 0, 0};
    float a1[8] = {0, 0, 0, 0, 0, 0, 0, 0};

    int2 e0 = ldnt2(&csr[beg]),     e1 = ldnt2(&csr[beg + 1]);
    int2 e2 = ldnt2(&csr[beg + 2]), e3 = ldnt2(&csr[beg + 3]);
    int j = beg;
    while (j + 4 <= end) {
        uint4 x0 = ego_in[(size_t)e0.x * 8 + l];
        uint4 x1 = ego_in[(size_t)e1.x * 8 + l];
        uint4 x2 = ego_in[(size_t)e2.x * 8 + l];
        uint4 x3 = ego_in[(size_t)e3.x * 8 + l];
        int2 n0 = ldnt2(&csr[j + 4]), n1 = ldnt2(&csr[j + 5]);
        int2 n2 = ldnt2(&csr[j + 6]), n3 = ldnt2(&csr[j + 7]);
        fma8(a0, __int_as_float(e0.y), x0);
        fma8(a1, __int_as_float(e1.y), x1);
        fma8(a0, __int_as_float(e2.y), x2);
        fma8(a1, __int_as_float(e3.y), x3);
        e0 = n0; e1 = n1; e2 = n2; e3 = n3;
        j += 4;
    }
    int rem = end - j;  // 0..3
    if (rem > 0) fma8(a0, __int_as_float(e0.y), ego_in[(size_t)e0.x * 8 + l]);
    if (rem > 1) fma8(a1, __int_as_float(e1.y), ego_in[(size_t)e1.x * 8 + l]);
    if (rem > 2) fma8(a0, __int_as_float(e2.y), ego_in[(size_t)e2.x * 8 + l]);

    float acc[8];
#pragma unroll
    for (int k = 0; k < 8; ++k) acc[k] = a0[k] + a1[k];

    if (!FINAL) {
        uint4 r;
        r.x = pack2(acc[0], acc[1]); r.y = pack2(acc[2], acc[3]);
        r.z = pack2(acc[4], acc[5]); r.w = pack2(acc[6], acc[7]);
        ego_out[(size_t)node * 8 + l] = r;
    } else {
        uint4 a = egoA[(size_t)node * 8 + l];
        uint4 b = egoB[(size_t)node * 8 + l];
        const float s = 1.0f / 3.0f;
        fx4 o0, o1;
        o0.x = (blo(a.x) + blo(b.x) + acc[0]) * s;
        o0.y = (bhi(a.x) + bhi(b.x) + acc[1]) * s;
        o0.z = (blo(a.y) + blo(b.y) + acc[2]) * s;
        o0.w = (bhi(a.y) + bhi(b.y) + acc[3]) * s;
        o1.x = (blo(a.z) + blo(b.z) + acc[4]) * s;
        o1.y = (bhi(a.z) + bhi(b.z) + acc[5]) * s;
        o1.z = (blo(a.w) + blo(b.w) + acc[6]) * s;
        o1.w = (bhi(a.w) + bhi(b.w) + acc[7]) * s;
        // out is written once and never re-read -> non-temporal
        size_t ob = (size_t)node * D_DIM + 8 * (size_t)l;
        __builtin_nontemporal_store(o0, (fx4*)&out[ob]);
        __builtin_nontemporal_store(o1, (fx4*)&out[ob + 4]);
    }
}

static inline size_t align_up(size_t x, size_t a) { return (x + a - 1) & ~(a - 1); }

extern "C" void kernel_launch(void* const* d_in, const int* in_sizes, int n_in,
                              void* d_out, int out_size, void* d_ws, size_t ws_size,
                              hipStream_t stream) {
    const float* user_emb  = (const float*)d_in[0];
    const float* item_emb  = (const float*)d_in[1];
    const int*   edge_src  = (const int*)d_in[2];
    const int*   edge_dst  = (const int*)d_in[3];
    const float* edge_vals = (const float*)d_in[4];
    const int    nE        = in_sizes[2];  // 2E = 1.2M

    float* out = (float*)d_out;
    const size_t nd = (size_t)N_NODES * D_DIM;

    const int NB_B = (nE + CHUNK - 1) / CHUNK;           // 293
    const int nH   = NBKT * NB_B;                        // ~172K
    const int NBs  = (nH + SCAN_BLK - 1) / SCAN_BLK;     // ~336

    // ---- ws layout ----
    size_t off = 0;
    char* base = (char*)d_ws;
    int2*  csr     = (int2*)(base + off);  off = align_up(off + (size_t)(nE + 4) * sizeof(int2), 256);
    int*   row_ptr = (int*)(base + off);   off = align_up(off + (size_t)(N_NODES + 1) * 4, 256);
    uint2* tmp     = (uint2*)(base + off); off = align_up(off + (size_t)nE * sizeof(uint2), 256);
    int*   H       = (int*)(base + off);   off = align_up(off + (size_t)nH * 4, 256);
    int*   blksum  = (int*)(base + off);   off = align_up(off + (size_t)NBs * 4, 256);
    uint4* ego0    = (uint4*)(base + off); off = align_up(off + (size_t)N_NODES * 128, 256);
    uint4* ego_a   = (uint4*)(base + off); off = align_up(off + (size_t)N_NODES * 128, 256);
    uint4* ego_b   = (uint4*)(base + off); off = align_up(off + (size_t)N_NODES * 128, 256);

    const int block = 256;
    const int n4  = (int)(nd / 4);
    const int n4u = U_CNT * D_DIM / 4;

    // ---- atomic-free CSR build (5 dispatches) ----
    bucket_hist<<<NB_B, block, 0, stream>>>(edge_dst, H, NB_B, nE,
        (const fx4*)user_emb, (const fx4*)item_emb, (uint2*)ego0, n4u, n4);
    block_sums<<<NBs, SCAN_BLK, 0, stream>>>(H, blksum, nH);
    scan_within<<<NBs, SCAN_BLK, 0, stream>>>(H, blksum, nH);
    bucket_scatter<<<NB_B, block, 0, stream>>>(edge_src, edge_dst, edge_vals, H, tmp, NB_B, nE);
    bucket_build<<<NBKT, block, 0, stream>>>(H, tmp, csr, row_ptr, NB_B, nE);

    // ---- 3 SpMM layers (bf16 gather, 8 lanes/node, x4 unroll) ----
    const size_t threads = (size_t)N_NODES * 8;
    const int spmm_grid = (int)((threads + block - 1) / block);

    lgcn_spmm<0><<<spmm_grid, block, 0, stream>>>(
        row_ptr, csr, ego0, ego_a, nullptr, nullptr, nullptr);
    lgcn_spmm<0><<<spmm_grid, block, 0, stream>>>(
        row_ptr, csr, ego_a, ego_b, nullptr, nullptr, nullptr);
    lgcn_spmm<1><<<spmm_grid, block, 0, stream>>>(
        row_ptr, csr, ego_b, nullptr, ego_a, ego_b, out);
}